// Round 1
// baseline (205.729 us; speedup 1.0000x reference)
//
#include <hip/hip_runtime.h>
#include <math.h>

#define N_IMG 32
#define C_CH  256
#define H     56
#define W     56
#define HW    (H * W)          // 3136
#define CHW   (C_CH * HW)      // 802816
#define HW4   (HW / 4)         // 784
#define TOTAL4 (N_IMG * CHW / 4)  // 6,422,528

// ---------------------------------------------------------------------------
// Kernel A: per-(n,h,w) channel mean and max over C=256.
// Block = 256 threads: 8 channel-subgroups x 32 float4-positions.
// Each thread loads 32 channels x float4 (coalesced 16B/lane), LDS-reduces
// 8-way across subgroups.
// ---------------------------------------------------------------------------
__global__ __launch_bounds__(256) void reduce_kernel(
    const float* __restrict__ x,
    float* __restrict__ avg_map,
    float* __restrict__ max_map)
{
    const int n   = blockIdx.y;
    const int tid = threadIdx.x;
    const int sub = tid >> 5;       // 0..7 channel subgroup
    const int pos = tid & 31;       // 0..31 position within chunk
    const int p4  = blockIdx.x * 32 + pos;   // float4 index within image
    const bool active = (p4 < HW4);

    float4 s = make_float4(0.f, 0.f, 0.f, 0.f);
    float4 m = make_float4(-INFINITY, -INFINITY, -INFINITY, -INFINITY);

    if (active) {
        const float* px = x + (size_t)n * CHW + (size_t)(sub * 32) * HW + (size_t)p4 * 4;
        #pragma unroll 8
        for (int i = 0; i < 32; ++i) {
            float4 v = *reinterpret_cast<const float4*>(px + (size_t)i * HW);
            s.x += v.x; s.y += v.y; s.z += v.z; s.w += v.w;
            m.x = fmaxf(m.x, v.x); m.y = fmaxf(m.y, v.y);
            m.z = fmaxf(m.z, v.z); m.w = fmaxf(m.w, v.w);
        }
    }

    __shared__ float4 ssum[256];
    __shared__ float4 smax[256];
    ssum[tid] = s;
    smax[tid] = m;
    __syncthreads();

    if (tid < 32) {
        // combine sums for position tid
        const int myp4 = blockIdx.x * 32 + tid;
        if (myp4 < HW4) {
            float4 a = ssum[tid];
            #pragma unroll
            for (int k = 1; k < 8; ++k) {
                float4 v = ssum[tid + k * 32];
                a.x += v.x; a.y += v.y; a.z += v.z; a.w += v.w;
            }
            const float inv = 1.0f / 256.0f;
            a.x *= inv; a.y *= inv; a.z *= inv; a.w *= inv;
            *reinterpret_cast<float4*>(avg_map + (size_t)n * HW + (size_t)myp4 * 4) = a;
        }
    } else if (tid < 64) {
        const int p = tid - 32;
        const int myp4 = blockIdx.x * 32 + p;
        if (myp4 < HW4) {
            float4 a = smax[p];
            #pragma unroll
            for (int k = 1; k < 8; ++k) {
                float4 v = smax[p + k * 32];
                a.x = fmaxf(a.x, v.x); a.y = fmaxf(a.y, v.y);
                a.z = fmaxf(a.z, v.z); a.w = fmaxf(a.w, v.w);
            }
            *reinterpret_cast<float4*>(max_map + (size_t)n * HW + (size_t)myp4 * 4) = a;
        }
    }
}

// ---------------------------------------------------------------------------
// Kernel B: 7x7 conv over [avg;max] (2 input channels) + bias + sigmoid.
// Grid (7, 32): one block per (image, 8-row chunk). Stages 14 rows x 62 cols
// (3-col zero pad each side) of both maps in LDS; zero-fill implements the
// conv's zero padding.
// ---------------------------------------------------------------------------
#define LDSW 62   // 56 + 3 pad each side
__global__ __launch_bounds__(256) void conv_kernel(
    const float* __restrict__ avg_map,
    const float* __restrict__ max_map,
    const float* __restrict__ w,   // [1][2][7][7] OIHW
    const float* __restrict__ b,   // [1]
    float* __restrict__ scale)
{
    const int n  = blockIdx.y;
    const int ry = blockIdx.x;          // row chunk: rows ry*8 .. ry*8+7
    const int tid = threadIdx.x;

    __shared__ float s_in[2][14][LDSW];
    __shared__ float s_w[98];
    __shared__ float s_b;

    float* s_raw = &s_in[0][0][0];
    for (int e = tid; e < 2 * 14 * LDSW; e += 256) s_raw[e] = 0.0f;
    if (tid < 98) s_w[tid] = w[tid];
    if (tid == 0) s_b = b[0];
    __syncthreads();

    for (int e = tid; e < 2 * 14 * 56; e += 256) {
        const int ch  = e / (14 * 56);
        const int r   = (e / 56) % 14;
        const int col = e % 56;
        const int gr  = ry * 8 - 3 + r;
        if (gr >= 0 && gr < H) {
            const float* src = (ch == 0) ? avg_map : max_map;
            s_in[ch][r][col + 3] = src[(size_t)n * HW + gr * W + col];
        }
    }
    __syncthreads();

    for (int o = tid; o < 8 * 56; o += 256) {
        const int r   = o / 56;        // 0..7
        const int col = o % 56;
        float acc = s_b;
        #pragma unroll
        for (int ch = 0; ch < 2; ++ch)
            #pragma unroll
            for (int i = 0; i < 7; ++i)
                #pragma unroll
                for (int j = 0; j < 7; ++j)
                    acc = fmaf(s_in[ch][r + i][col + j], s_w[ch * 49 + i * 7 + j], acc);
        const float sc = 1.0f / (1.0f + expf(-acc));
        scale[(size_t)n * HW + (ry * 8 + r) * W + col] = sc;
    }
}

// ---------------------------------------------------------------------------
// Kernel C: out = x * scale (scale broadcast over 256 channels).
// Grid-stride float4; scale map (401 KB) stays L2-resident.
// ---------------------------------------------------------------------------
__global__ __launch_bounds__(256) void apply_kernel(
    const float* __restrict__ x,
    const float* __restrict__ scale,
    float* __restrict__ out)
{
    const unsigned stride = gridDim.x * 256u;
    for (unsigned i = blockIdx.x * 256u + threadIdx.x; i < TOTAL4; i += stride) {
        const unsigned n    = i / (CHW / 4);            // /200704 -> magic mul
        const unsigned rem  = i - n * (CHW / 4);
        const unsigned hw4  = rem % HW4;                // %784 -> magic mul
        const float4 sc = *reinterpret_cast<const float4*>(scale + (size_t)n * HW + (size_t)hw4 * 4);
        float4 v = reinterpret_cast<const float4*>(x)[i];
        v.x *= sc.x; v.y *= sc.y; v.z *= sc.z; v.w *= sc.w;
        reinterpret_cast<float4*>(out)[i] = v;
    }
}

extern "C" void kernel_launch(void* const* d_in, const int* in_sizes, int n_in,
                              void* d_out, int out_size, void* d_ws, size_t ws_size,
                              hipStream_t stream)
{
    const float* x = (const float*)d_in[0];   // 25,690,112 floats
    const float* w = (const float*)d_in[1];   // 98 floats (1,2,7,7)
    const float* b = (const float*)d_in[2];   // 1 float
    float* out = (float*)d_out;

    float* ws       = (float*)d_ws;
    float* avg_map  = ws;                       // 100,352 floats
    float* max_map  = ws + (size_t)N_IMG * HW;  // 100,352 floats
    float* scale    = ws + (size_t)2 * N_IMG * HW; // 100,352 floats (1.2 MB total)

    dim3 gA((HW4 + 31) / 32, N_IMG);   // (25, 32)
    reduce_kernel<<<gA, 256, 0, stream>>>(x, avg_map, max_map);

    dim3 gB(H / 8, N_IMG);             // (7, 32)
    conv_kernel<<<gB, 256, 0, stream>>>(avg_map, max_map, w, b, scale);

    apply_kernel<<<2048, 256, 0, stream>>>(x, scale, out);
}